// Round 3
// baseline (4775.161 us; speedup 1.0000x reference)
//
#include <hip/hip_runtime.h>
#include <math.h>

// Problem constants (match setup_inputs in the reference).
#define B_SZ   32
#define T_SZ   400
#define D_SZ   2048
#define S_DEN  2000
#define E_DEN  60000
#define S_NUM  512
#define E_NUM  2048
#define DEN_C  1e-5f
#define NUM_C  1e-20f

#define P_CH   4          // den edge-chunks (CUs) per utterance-pair group
#define PGRP   16         // den groups; group g owns utterances {2g, 2g+1}
#define NTHR   512        // threads per block (8 waves)
#define EPT    32         // edges per thread (per utterance pass)
#define EPC    16384      // padded edges per chunk = NTHR*EPT

// ---- workspace layout (bytes). Overlays are time-disjoint:
//   REC (prep only) is overlaid by ANEWG (main only).
#define REC_OFF     0u          // int4[E_DEN] CSR {in,pdf,prob,out} sorted by out
#define ANEWG_OFF   0u          // float[B][2][2048] exchange buffer (524,288 B)
#define PACK_OFF    960000u     // uint2[P_CH*EPC] packed {in|pdf<<11|drow<<22, prob}
#define ROWPTR_OFF  1484288u    // int[S_DEN+1]
#define CNT_OFF     1492352u    // int[S_DEN]
#define SROW_OFF    1492352u    // int[P_CH*NTHR] per-(chunk,thread) start row
#define CUR_OFF     1500352u    // int[S_DEN]
#define RSPLIT_OFF  1508352u    // int[P_CH+1] chunk row splits
#define PSUM_OFF    1508416u    // float[B][2][P_CH] partial asums
#define FLAG_OFF    1509440u    // int[B][P_CH] monotonic seq flags (=t+1)
#define TOTD_OFF    1509952u    // float[B]
#define TOTN_OFF    1510080u    // float[B]
#define WS_BYTES    1510208u

__device__ __forceinline__ float expclip(float v) {
    return __expf(fminf(fmaxf(v, -30.f), 30.f));
}
// Agent-scope (device-coherent) accesses: relaxed atomics emit sc-bit
// write-through/bypass memory ops WITHOUT whole-L2 writeback/invalidate.
__device__ __forceinline__ float ldf_agent(const float* p) {
    return __hip_atomic_load(p, __ATOMIC_RELAXED, __HIP_MEMORY_SCOPE_AGENT);
}
__device__ __forceinline__ int ldi_agent(const int* p) {
    return __hip_atomic_load(p, __ATOMIC_RELAXED, __HIP_MEMORY_SCOPE_AGENT);
}
__device__ __forceinline__ void stf_agent(float* p, float v) {
    __hip_atomic_store(p, v, __ATOMIC_RELAXED, __HIP_MEMORY_SCOPE_AGENT);
}
__device__ __forceinline__ void sti_agent(int* p, int v) {
    __hip_atomic_store(p, v, __ATOMIC_RELAXED, __HIP_MEMORY_SCOPE_AGENT);
}

// ---------------- prep kernels ----------------
__global__ void prep_init(char* ws) {
    int tid = threadIdx.x;
    int* cnt = (int*)(ws + CNT_OFF);
    int* cur = (int*)(ws + CUR_OFF);
    for (int i = tid; i < S_DEN; i += 256) { cnt[i] = 0; cur[i] = 0; }
    int* flags = (int*)(ws + FLAG_OFF);
    if (tid < B_SZ * P_CH) flags[tid] = 0;   // seq flags (ws re-poisoned each launch)
}

__global__ void prep_hist(const int* __restrict__ e_out, char* ws) {
    int e = blockIdx.x * blockDim.x + threadIdx.x;
    if (e < E_DEN) atomicAdd((int*)(ws + CNT_OFF) + e_out[e], 1);
}

__global__ __launch_bounds__(1024) void prep_scan(char* ws) {
    __shared__ int sb[2][2048];
    const int* cnt = (const int*)(ws + CNT_OFF);
    int* rowp = (int*)(ws + ROWPTR_OFF);
    int tid = threadIdx.x;
    for (int i = tid; i < 2048; i += 1024) sb[0][i] = (i < S_DEN) ? cnt[i] : 0;
    __syncthreads();
    int cur = 0;
    for (int d = 1; d < 2048; d <<= 1) {
        for (int i = tid; i < 2048; i += 1024)
            sb[1 - cur][i] = sb[cur][i] + ((i >= d) ? sb[cur][i - d] : 0);
        __syncthreads();
        cur ^= 1;
    }
    if (tid == 0) rowp[0] = 0;
    for (int i = tid; i < S_DEN; i += 1024) rowp[i + 1] = sb[cur][i];
    __syncthreads();
    if (tid == 0) {
        // Row splits at ~equal edge counts: chunk p owns rows [rs[p], rs[p+1]).
        int* rs = (int*)(ws + RSPLIT_OFF);
        rs[0] = 0; rs[P_CH] = S_DEN;
        for (int p = 1; p < P_CH; ++p) {
            int target = (E_DEN / P_CH) * p;
            int lo = 0, hi = S_DEN;
            while (lo < hi) {
                int mid = (lo + hi) >> 1;
                int v = (mid == 0) ? 0 : sb[cur][mid - 1];   // rowp[mid]
                if (v >= target) hi = mid; else lo = mid + 1;
            }
            rs[p] = lo;
        }
    }
}

__global__ void prep_scatter(const int* __restrict__ e_in, const int* __restrict__ e_out,
                             const int* __restrict__ e_pdf, const float* __restrict__ e_prob,
                             char* ws) {
    int e = blockIdx.x * blockDim.x + threadIdx.x;
    if (e >= E_DEN) return;
    const int* rowp = (const int*)(ws + ROWPTR_OFF);
    int* cur = (int*)(ws + CUR_OFF);
    int4* recs = (int4*)(ws + REC_OFF);
    int o = e_out[e];
    int pos = rowp[o] + atomicAdd(&cur[o], 1);
    int4 r;
    r.x = e_in[e]; r.y = e_pdf[e];
    r.z = __float_as_int(e_prob[e]);
    r.w = o;
    recs[pos] = r;
}

// Pack per-chunk, padded to EPC with dummies (prob=0,d=0); srow per (chunk,thread).
__global__ void prep_pack(char* ws) {
    int slot = blockIdx.x * blockDim.x + threadIdx.x;
    if (slot >= P_CH * EPC) return;
    int p = slot >> 14;            // EPC = 16384
    int k = slot & (EPC - 1);
    const int* rowp = (const int*)(ws + ROWPTR_OFF);
    const int* rs = (const int*)(ws + RSPLIT_OFF);
    int ebase = rowp[rs[p]], eend = rowp[rs[p + 1]];
    uint2* pk = (uint2*)(ws + PACK_OFF);
    int idx = ebase + k;
    uint2 val;
    int myrow;
    if (idx < eend) {
        const int4* r4 = (const int4*)(ws + REC_OFF);
        int4 r = r4[idx];
        myrow = r.w;
        int nxt = (idx + 1 < eend) ? r4[idx + 1].w : myrow;  // chunk-last: d=0
        unsigned d = (unsigned)(nxt - myrow);
        if (d > 1023u) d = 1023u;                            // unreachable here
        val = make_uint2((unsigned)r.x | ((unsigned)r.y << 11) | (d << 22),
                         (unsigned)r.z);
    } else {
        val = make_uint2(0u, 0u);
        myrow = rs[p];
    }
    pk[slot] = val;
    if ((k & (EPT - 1)) == 0)
        ((int*)(ws + SROW_OFF))[(p << 9) + (k >> 5)] = myrow;
}

// Edge pass over this chunk's 32 edges for one utterance (LDS bases ALD/XLD/NLD).
// Leaves per-wave psum partials in red[0..7]. Uses/rotates c0..c7 prefetch regs.
#define EDGE_PASS(ALD, XLD, NLD)                                               \
  {                                                                            \
    float acc = 0.f, psum = 0.f;                                               \
    int row = row0;                                                            \
    _Pragma("unroll")                                                          \
    for (int sb = 0; sb < 2; ++sb) {                                           \
      const int nq = qb + (((sb + 1) & 1) << 3);                               \
      uint4 n0 = pk4[nq + 0], n1 = pk4[nq + 1], n2 = pk4[nq + 2], n3 = pk4[nq + 3]; \
      uint4 n4 = pk4[nq + 4], n5 = pk4[nq + 5], n6 = pk4[nq + 6], n7 = pk4[nq + 7]; \
      const unsigned w[16] = {c0.x, c0.z, c1.x, c1.z, c2.x, c2.z, c3.x, c3.z,  \
                              c4.x, c4.z, c5.x, c5.z, c6.x, c6.z, c7.x, c7.z}; \
      const unsigned pr[16] = {c0.y, c0.w, c1.y, c1.w, c2.y, c2.w, c3.y, c3.w, \
                               c4.y, c4.w, c5.y, c5.w, c6.y, c6.w, c7.y, c7.w};\
      float av[16], xv[16];                                                    \
      _Pragma("unroll")                                                        \
      for (int i = 0; i < 16; ++i) av[i] = (ALD)[w[i] & 2047u];                \
      _Pragma("unroll")                                                        \
      for (int i = 0; i < 16; ++i) xv[i] = (XLD)[(w[i] >> 11) & 2047u];        \
      _Pragma("unroll")                                                        \
      for (int i = 0; i < 16; ++i) {                                           \
        acc = __fmaf_rn(av[i] * __uint_as_float(pr[i]), xv[i], acc);           \
        const unsigned d = w[i] >> 22;                                         \
        if (d) { psum += acc; atomicAdd(&(NLD)[row], acc); acc = 0.f; row += (int)d; } \
      }                                                                        \
      c0 = n0; c1 = n1; c2 = n2; c3 = n3;                                      \
      c4 = n4; c5 = n5; c6 = n6; c7 = n7;                                      \
    }                                                                          \
    psum += acc;                                                               \
    if (acc != 0.f) atomicAdd(&(NLD)[row], acc);                               \
    _Pragma("unroll")                                                          \
    for (int o = 32; o > 0; o >>= 1) psum += __shfl_down(psum, o, 64);         \
    if ((tid & 63) == 0) red[tid >> 6] = psum;                                 \
  }

// ---------------- main kernel: 64 den blocks (16 groups x 4 chunks) + 32 num --
// Each den group runs TWO utterances interleaved per round so the cross-block
// exchange latency of one hides under the other's edge phase. Group barrier =
// monotonic per-(utt,chunk) seq flags (store after vmcnt drain; 4-lane poll).
__global__ __launch_bounds__(NTHR, 2) void chain_fwd4(
    const float* __restrict__ x, const int* __restrict__ lengths,
    const float* __restrict__ den_leaky, const float* __restrict__ den_final,
    const int* __restrict__ num_in, const int* __restrict__ num_out,
    const int* __restrict__ num_pdf, const float* __restrict__ num_prob,
    const float* __restrict__ num_leaky, const float* __restrict__ num_final,
    char* __restrict__ ws)
{
    __shared__ float sAlpha[2][2048];
    __shared__ float sXrow[2][2048];
    __shared__ float sAnew[2][2048];
    __shared__ float red[16];
    extern __shared__ float dynpad[];    // 40 KB occupancy pad (1 block/CU)
    const int tid = threadIdx.x;
    if (lengths[0] == -12345) dynpad[tid] = 1.f;   // never true; keeps pad live

    if (blockIdx.x < P_CH * PGRP) {
        // =============== den chunk block: utterances bA=2g, bB=2g+1 ===========
        const int g = blockIdx.x & (PGRP - 1);     // blockIdx = p*16+g: same XCD
        const int p = blockIdx.x >> 4;             // for all chunks of a group
        const int bA = 2 * g, bB = 2 * g + 1;
        const int lenA = lengths[bA], lenB = lengths[bB];   // lenA >= lenB
        const float* xA = x + (size_t)bA * T_SZ * D_SZ;
        const float* xB = x + (size_t)bB * T_SZ * D_SZ;
        const int* rs = (const int*)(ws + RSPLIT_OFF);
        const int rlo = rs[p], rhi = rs[p + 1];
        float* anewg = (float*)(ws + ANEWG_OFF);
        float* psumg = (float*)(ws + PSUM_OFF);
        int* flags   = (int*)(ws + FLAG_OFF);

        // Hoisted per-state constants (4 states/thread; shared den graph =>
        // identical for both utterances).
        float lc[4], fc[4];
        #pragma unroll
        for (int i = 0; i < 4; ++i) {
            int s = tid + (i << 9);
            lc[i] = (s < S_DEN) ? DEN_C * den_leaky[s] : 0.f;
            fc[i] = (s < S_DEN) ? den_final[s] : 0.f;
        }
        #pragma unroll
        for (int i = 0; i < 4; ++i) {
            int s = tid + (i << 9);
            float a0 = lc[i] + ((s == 0) ? 1.f : 0.f);   // adash0 (asum=1)
            sAlpha[0][s] = a0; sAlpha[1][s] = a0;
            sAnew[0][s] = 0.f; sAnew[1][s] = 0.f;
            sXrow[0][s] = expclip(xA[s]);
            sXrow[1][s] = expclip(xB[s]);
        }

        const uint4* __restrict__ pk4 = (const uint4*)(ws + PACK_OFF);
        const int qb = (p << 13) + (tid << 4);   // uint4 index of my 32 edges
        const int row0 = ((const int*)(ws + SROW_OFF))[(p << 9) + tid];
        float logzA = 0.f, logzB = 0.f;
        // Superbatch-0 (16 edges) prefetched; rotates across passes/rounds.
        uint4 c0 = pk4[qb + 0], c1 = pk4[qb + 1], c2 = pk4[qb + 2], c3 = pk4[qb + 3];
        uint4 c4 = pk4[qb + 4], c5 = pk4[qb + 5], c6 = pk4[qb + 6], c7 = pk4[qb + 7];
        __syncthreads();

        for (int t = 0; t < lenA; ++t) {
            const bool haveB = (t < lenB);
            const int par = t & 1;

            // Prefetch x(t+1) for both utterances (consumed at stage, pre-spin).
            const int tnA = (t + 1 < lenA) ? t + 1 : t;
            const float* xqA = xA + (size_t)tnA * D_SZ;
            const float xa0 = xqA[tid],        xa1 = xqA[tid + 512];
            const float xa2 = xqA[tid + 1024], xa3 = xqA[tid + 1536];
            float xb0 = 0.f, xb1 = 0.f, xb2 = 0.f, xb3 = 0.f;
            if (haveB) {
                const int tnB = (t + 1 < lenB) ? t + 1 : t;
                const float* xqB = xB + (size_t)tnB * D_SZ;
                xb0 = xqB[tid];        xb1 = xqB[tid + 512];
                xb2 = xqB[tid + 1024]; xb3 = xqB[tid + 1536];
            }

            // ---- utterance A: edge + publish ----
            EDGE_PASS(sAlpha[0], sXrow[0], sAnew[0]);
            __syncthreads();                               // anewA + red ready
            {
                float* ag = anewg + (size_t)(((bA << 1) | par) << 11);
                if (tid == 0) {
                    float bs = red[0]+red[1]+red[2]+red[3]+red[4]+red[5]+red[6]+red[7];
                    stf_agent(&psumg[(((bA << 1) | par) << 2) + p], bs);
                }
                for (int r = rlo + tid; r < rhi; r += NTHR) {
                    stf_agent(&ag[r], sAnew[0][r]); sAnew[0][r] = 0.f;
                }
                asm volatile("s_waitcnt vmcnt(0)" ::: "memory");  // per-wave drain
            }
            __syncthreads();                               // all waves drained
            if (tid == 0) sti_agent(&flags[(bA << 2) + p], t + 1);  // release A

            // ---- utterance B: edge + publish (hides A's flag propagation) ----
            if (haveB) {
                EDGE_PASS(sAlpha[1], sXrow[1], sAnew[1]);
                __syncthreads();
                {
                    float* ag = anewg + (size_t)(((bB << 1) | par) << 11);
                    if (tid == 0) {
                        float bs = red[0]+red[1]+red[2]+red[3]+red[4]+red[5]+red[6]+red[7];
                        stf_agent(&psumg[(((bB << 1) | par) << 2) + p], bs);
                    }
                    for (int r = rlo + tid; r < rhi; r += NTHR) {
                        stf_agent(&ag[r], sAnew[1][r]); sAnew[1][r] = 0.f;
                    }
                    asm volatile("s_waitcnt vmcnt(0)" ::: "memory");
                }
                __syncthreads();
                if (tid == 0) sti_agent(&flags[(bB << 2) + p], t + 1);  // release B
            }

            // Stage xrow(t+1) while peer chunks finish publishing.
            sXrow[0][tid]        = expclip(xa0);
            sXrow[0][tid + 512]  = expclip(xa1);
            sXrow[0][tid + 1024] = expclip(xa2);
            sXrow[0][tid + 1536] = expclip(xa3);
            if (haveB) {
                sXrow[1][tid]        = expclip(xb0);
                sXrow[1][tid + 512]  = expclip(xb1);
                sXrow[1][tid + 1024] = expclip(xb2);
                sXrow[1][tid + 1536] = expclip(xb3);
            }

            // Parallel 4-lane spins (A in wave0, B in wave1); fetch psums.
            if (tid < 4) {
                const int fi = (bA << 2) + tid; int gd = 0;
                while (ldi_agent(&flags[fi]) < t + 1) {
                    __builtin_amdgcn_s_sleep(1);
                    if (++gd > (1 << 15)) break;           // bail, don't hang
                }
                red[8 + tid] = ldf_agent(&psumg[(((bA << 1) | par) << 2) + tid]);
            } else if (haveB && tid >= 64 && tid < 68) {
                const int q = tid - 64;
                const int fi = (bB << 2) + q; int gd = 0;
                while (ldi_agent(&flags[fi]) < t + 1) {
                    __builtin_amdgcn_s_sleep(1);
                    if (++gd > (1 << 15)) break;
                }
                red[12 + q] = ldf_agent(&psumg[(((bB << 1) | par) << 2) + q]);
            }
            __syncthreads();                               // psums + flags seen

            // Consume A: full anew -> adash -> alpha.
            {
                const float asum = red[8] + red[9] + red[10] + red[11];
                const float inv = 1.f / asum;
                const float* ag = anewg + (size_t)(((bA << 1) | par) << 11);
                #pragma unroll
                for (int i = 0; i < 4; ++i) {
                    const int s = tid + (i << 9);
                    float an = (s < S_DEN) ? ldf_agent(&ag[s]) : 0.f;
                    sAlpha[0][s] = __fmaf_rn(an, inv, lc[i]);
                }
                logzA += logf(asum);
            }
            if (haveB) {
                const float asum = red[12] + red[13] + red[14] + red[15];
                const float inv = 1.f / asum;
                const float* ag = anewg + (size_t)(((bB << 1) | par) << 11);
                #pragma unroll
                for (int i = 0; i < 4; ++i) {
                    const int s = tid + (i << 9);
                    float an = (s < S_DEN) ? ldf_agent(&ag[s]) : 0.f;
                    sAlpha[1][s] = __fmaf_rn(an, inv, lc[i]);
                }
                logzB += logf(asum);
            }
            __syncthreads();                               // alpha/xrow ready
        }

        if (p == 0) {   // final dots over full alpha (resident in LDS)
            #pragma unroll
            for (int u = 0; u < 2; ++u) {
                const int b = (u == 0) ? bA : bB;
                const float logz = (u == 0) ? logzA : logzB;
                float fs = sAlpha[u][tid] * fc[0] + sAlpha[u][tid + 512] * fc[1]
                         + sAlpha[u][tid + 1024] * fc[2] + sAlpha[u][tid + 1536] * fc[3];
                #pragma unroll
                for (int o = 32; o > 0; o >>= 1) fs += __shfl_down(fs, o, 64);
                if ((tid & 63) == 0) red[tid >> 6] = fs;
                __syncthreads();
                if (tid == 0) {
                    float tot = red[0]+red[1]+red[2]+red[3]+red[4]+red[5]+red[6]+red[7];
                    ((float*)(ws + TOTD_OFF))[b] = logz + logf(tot);
                }
                __syncthreads();
            }
        }
    } else {
        // =============== num: one block per utterance, LDS-local ===============
        const int b = blockIdx.x - P_CH * PGRP;
        const int len = lengths[b];
        const float* xb = x + (size_t)b * T_SZ * D_SZ;
        float* nalpha = &sAlpha[0][0];    // [512]
        float* nanew  = &sAnew[0][0];     // [512]
        float* xrow   = &sXrow[0][0];     // [2048]
        const float lk = num_leaky[(b << 9) + tid];
        const float fn = num_final[(b << 9) + tid];
        // Hoist this utterance's edges into registers (4 edges/thread).
        int ein[4], eout[4], epdf[4]; float eprb[4];
        #pragma unroll
        for (int k = 0; k < 4; ++k) {
            int e = (b << 11) + tid + (k << 9);
            ein[k] = num_in[e]; eout[k] = num_out[e];
            epdf[k] = num_pdf[e]; eprb[k] = num_prob[e];
        }
        nalpha[tid] = NUM_C * lk + ((tid == 0) ? 1.f : 0.f);
        nanew[tid] = 0.f;
        #pragma unroll
        for (int i = 0; i < 4; ++i) xrow[tid + (i << 9)] = expclip(xb[tid + (i << 9)]);
        float logz = 0.f;
        __syncthreads();

        for (int t = 0; t < len; ++t) {
            const int tn = (t + 1 < len) ? t + 1 : t;
            const float* xq = xb + (size_t)tn * D_SZ;
            const float xn0 = xq[tid], xn1 = xq[tid + 512];
            const float xn2 = xq[tid + 1024], xn3 = xq[tid + 1536];
            #pragma unroll
            for (int k = 0; k < 4; ++k) {
                float v = nalpha[ein[k]] * eprb[k] * xrow[epdf[k]];
                atomicAdd(&nanew[eout[k]], v);
            }
            __syncthreads();
            float ps = nanew[tid];
            #pragma unroll
            for (int o = 32; o > 0; o >>= 1) ps += __shfl_down(ps, o, 64);
            if ((tid & 63) == 0) red[tid >> 6] = ps;
            __syncthreads();
            float asum = 0.f;
            #pragma unroll
            for (int i = 0; i < 8; ++i) asum += red[i];
            nalpha[tid] = __fmaf_rn(NUM_C * lk, asum, nanew[tid]) * (1.f / asum);
            nanew[tid] = 0.f;
            xrow[tid]        = expclip(xn0);
            xrow[tid + 512]  = expclip(xn1);
            xrow[tid + 1024] = expclip(xn2);
            xrow[tid + 1536] = expclip(xn3);
            logz += logf(asum);
            __syncthreads();
        }
        float fs = nalpha[tid] * fn;
        #pragma unroll
        for (int o = 32; o > 0; o >>= 1) fs += __shfl_down(fs, o, 64);
        if ((tid & 63) == 0) red[tid >> 6] = fs;
        __syncthreads();
        if (tid == 0) {
            float tot = 0.f;
            #pragma unroll
            for (int i = 0; i < 8; ++i) tot += red[i];
            ((float*)(ws + TOTN_OFF))[b] = logz + logf(tot);
        }
    }
}

__global__ void combine2(const char* __restrict__ ws, const int* __restrict__ lengths,
                         float* __restrict__ out) {
    const float* totd = (const float*)(ws + TOTD_OFF);
    const float* totn = (const float*)(ws + TOTN_OFF);
    int tid = threadIdx.x;
    float v = 0.f, l = 0.f;
    if (tid < B_SZ) { v = totd[tid] - totn[tid]; l = (float)lengths[tid]; }
    #pragma unroll
    for (int o = 32; o > 0; o >>= 1) { v += __shfl_down(v, o, 64); l += __shfl_down(l, o, 64); }
    if (tid == 0) out[0] = v / l;
}

// ===================== round-1 fallback (used only if ws too small) ==========
__global__ __launch_bounds__(1024) void chain_fwd_kernel(
    const float* __restrict__ x, const int* __restrict__ lengths,
    const int* __restrict__ den_in, const int* __restrict__ den_out,
    const int* __restrict__ den_pdf, const float* __restrict__ den_prob,
    const float* __restrict__ den_leaky, const float* __restrict__ den_final,
    const int* __restrict__ num_in, const int* __restrict__ num_out,
    const int* __restrict__ num_pdf, const float* __restrict__ num_prob,
    const float* __restrict__ num_leaky, const float* __restrict__ num_final,
    float* __restrict__ part)
{
    __shared__ float xrow[D_SZ];
    __shared__ float alpha[S_DEN];
    __shared__ float anew[S_DEN];
    __shared__ float red[17];
    const int tid = threadIdx.x;
    const int nthr = 1024;
    const bool is_den = blockIdx.x < B_SZ;
    const int b = blockIdx.x & (B_SZ - 1);
    int S, E;
    const int *e_in, *e_out, *e_pdf;
    const float *e_prob, *leaky, *fin;
    float coeff;
    if (is_den) {
        S = S_DEN; E = E_DEN;
        e_in = den_in; e_out = den_out; e_pdf = den_pdf; e_prob = den_prob;
        leaky = den_leaky; fin = den_final; coeff = DEN_C;
    } else {
        S = S_NUM; E = E_NUM;
        e_in = num_in + b * E_NUM; e_out = num_out + b * E_NUM;
        e_pdf = num_pdf + b * E_NUM; e_prob = num_prob + b * E_NUM;
        leaky = num_leaky + b * S_NUM; fin = num_final + b * S_NUM;
        coeff = NUM_C;
    }
    const int len = lengths[b];
    const float* xb = x + (size_t)b * T_SZ * D_SZ;
    for (int s = tid; s < S; s += nthr)
        alpha[s] = coeff * leaky[s] + (s == 0 ? 1.0f : 0.0f);
    float logz = 0.0f;
    for (int t = 0; t < len; ++t) {
        for (int s = tid; s < S; s += nthr) anew[s] = 0.0f;
        const float* xt = xb + (size_t)t * D_SZ;
        for (int d = tid; d < D_SZ; d += nthr)
            xrow[d] = __expf(fminf(fmaxf(xt[d], -30.0f), 30.0f));
        __syncthreads();
        for (int e = tid; e < E; e += nthr) {
            float v = alpha[e_in[e]] * e_prob[e] * xrow[e_pdf[e]];
            atomicAdd(&anew[e_out[e]], v);
        }
        __syncthreads();
        float ps = 0.0f;
        for (int s = tid; s < S; s += nthr) ps += anew[s];
        #pragma unroll
        for (int off = 32; off > 0; off >>= 1) ps += __shfl_down(ps, off, 64);
        if ((tid & 63) == 0) red[tid >> 6] = ps;
        __syncthreads();
        if (tid < 64) {
            float v = (tid < 16) ? red[tid] : 0.0f;
            #pragma unroll
            for (int off = 8; off > 0; off >>= 1) v += __shfl_down(v, off, 64);
            if (tid == 0) red[16] = v;
        }
        __syncthreads();
        const float asum = red[16];
        const float inv = 1.0f / asum;
        for (int s = tid; s < S; s += nthr)
            alpha[s] = (anew[s] + coeff * leaky[s] * asum) * inv;
        logz += logf(asum);
        __syncthreads();
    }
    float fs = 0.0f;
    for (int s = tid; s < S; s += nthr) fs += alpha[s] * fin[s];
    #pragma unroll
    for (int off = 32; off > 0; off >>= 1) fs += __shfl_down(fs, off, 64);
    if ((tid & 63) == 0) red[tid >> 6] = fs;
    __syncthreads();
    if (tid < 64) {
        float v = (tid < 16) ? red[tid] : 0.0f;
        #pragma unroll
        for (int off = 8; off > 0; off >>= 1) v += __shfl_down(v, off, 64);
        if (tid == 0) part[blockIdx.x] = logz + logf(v);
    }
}

__global__ void combine_kernel(const float* __restrict__ part,
                               const int* __restrict__ lengths,
                               float* __restrict__ out)
{
    int tid = threadIdx.x;
    float v = 0.0f, l = 0.0f;
    if (tid < B_SZ) { v = part[tid] - part[B_SZ + tid]; l = (float)lengths[tid]; }
    #pragma unroll
    for (int off = 32; off > 0; off >>= 1) { v += __shfl_down(v, off, 64); l += __shfl_down(l, off, 64); }
    if (tid == 0) out[0] = v / l;
}

// ---------------------------------------------------------------------------
extern "C" void kernel_launch(void* const* d_in, const int* in_sizes, int n_in,
                              void* d_out, int out_size, void* d_ws, size_t ws_size,
                              hipStream_t stream)
{
    const float* x          = (const float*)d_in[0];
    const int*   lengths    = (const int*)  d_in[1];
    const int*   den_in_p   = (const int*)  d_in[2];
    const int*   den_out_p  = (const int*)  d_in[3];
    const int*   den_pdf_p  = (const int*)  d_in[4];
    const float* den_prob_p = (const float*)d_in[5];
    const float* den_leaky  = (const float*)d_in[6];
    const float* den_final  = (const float*)d_in[7];
    const int*   num_in_p   = (const int*)  d_in[8];
    const int*   num_out_p  = (const int*)  d_in[9];
    const int*   num_pdf_p  = (const int*)  d_in[10];
    const float* num_prob_p = (const float*)d_in[11];
    const float* num_leaky  = (const float*)d_in[12];
    const float* num_final  = (const float*)d_in[13];

    if (ws_size >= WS_BYTES) {
        char* ws = (char*)d_ws;
        hipLaunchKernelGGL(prep_init, dim3(1), dim3(256), 0, stream, ws);
        hipLaunchKernelGGL(prep_hist, dim3((E_DEN + 255) / 256), dim3(256), 0, stream,
                           den_out_p, ws);
        hipLaunchKernelGGL(prep_scan, dim3(1), dim3(1024), 0, stream, ws);
        hipLaunchKernelGGL(prep_scatter, dim3((E_DEN + 255) / 256), dim3(256), 0, stream,
                           den_in_p, den_out_p, den_pdf_p, den_prob_p, ws);
        hipLaunchKernelGGL(prep_pack, dim3((P_CH * EPC + 255) / 256), dim3(256), 0, stream, ws);
        // 40 KB dynamic pad: 48.1 KB static + 40 KB > 80 KB -> one block/CU, so
        // all 96 blocks co-resident (spin-safe) with private LDS pipes.
        hipLaunchKernelGGL(chain_fwd4, dim3(P_CH * PGRP + B_SZ), dim3(NTHR), 40960, stream,
                           x, lengths, den_leaky, den_final,
                           num_in_p, num_out_p, num_pdf_p, num_prob_p,
                           num_leaky, num_final, ws);
        hipLaunchKernelGGL(combine2, dim3(1), dim3(64), 0, stream,
                           ws, lengths, (float*)d_out);
    } else {
        float* part = (float*)d_ws;
        hipLaunchKernelGGL(chain_fwd_kernel, dim3(2 * B_SZ), dim3(1024), 0, stream,
                           x, lengths,
                           den_in_p, den_out_p, den_pdf_p, den_prob_p, den_leaky, den_final,
                           num_in_p, num_out_p, num_pdf_p, num_prob_p, num_leaky, num_final,
                           part);
        hipLaunchKernelGGL(combine_kernel, dim3(1), dim3(64), 0, stream,
                           part, lengths, (float*)d_out);
    }
}

// Round 4
// 2791.752 us; speedup vs baseline: 1.7105x; 1.7105x over previous
//
#include <hip/hip_runtime.h>
#include <math.h>

// Problem constants (match setup_inputs in the reference).
#define B_SZ   32
#define T_SZ   400
#define D_SZ   2048
#define S_DEN  2000
#define E_DEN  60000
#define S_NUM  512
#define E_NUM  2048
#define DEN_C  1e-5f
#define NUM_C  1e-20f

#define P_CH   4          // den edge-chunks (CUs) per utterance
#define NTHR   512        // threads per block (8 waves)
#define EPT    32         // edges per thread
#define EPC    16384      // padded edges per chunk = NTHR*EPT

// ---- workspace layout (bytes). Overlays are time-disjoint:
//   REC (prep only) is overlaid by ANEWG (main only).
#define REC_OFF     0u          // int4[E_DEN] CSR {in,pdf,prob,out} sorted by out
#define ANEWG_OFF   0u          // float[B][2][2048] exchange buffer (524,288 B)
#define PACK_OFF    960000u     // uint2[P_CH*EPC] packed {in|pdf<<11|drow<<22, prob}
#define ROWPTR_OFF  1484288u    // int[S_DEN+1]
#define CNT_OFF     1492352u    // int[S_DEN]
#define SROW_OFF    1492352u    // int[P_CH*NTHR] per-(chunk,thread) start row
#define CUR_OFF     1500352u    // int[S_DEN]
#define RSPLIT_OFF  1508352u    // int[P_CH+1] chunk row splits
#define PSUM_OFF    1508416u    // float[B][2][8] partial asums (64B/utt, padded)
#define CTR_OFF     1510464u    // int[B][16] arrive counters (64B/utt, padded)
#define TOTD_OFF    1512512u    // float[B]
#define TOTN_OFF    1512640u    // float[B]
#define WS_BYTES    1512768u

__device__ __forceinline__ float expclip(float v) {
    return __expf(fminf(fmaxf(v, -30.f), 30.f));
}
// Agent-scope (device-coherent) accesses: relaxed atomics emit sc-bit
// write-through/bypass memory ops WITHOUT whole-L2 writeback/invalidate
// (round-1 lesson: __threadfence costs a full L2 flush per call on gfx950).
__device__ __forceinline__ float ldf_agent(const float* p) {
    return __hip_atomic_load(p, __ATOMIC_RELAXED, __HIP_MEMORY_SCOPE_AGENT);
}
__device__ __forceinline__ int ldi_agent(const int* p) {
    return __hip_atomic_load(p, __ATOMIC_RELAXED, __HIP_MEMORY_SCOPE_AGENT);
}
__device__ __forceinline__ void stf_agent(float* p, float v) {
    __hip_atomic_store(p, v, __ATOMIC_RELAXED, __HIP_MEMORY_SCOPE_AGENT);
}

// ---------------- prep kernels ----------------
__global__ void prep_init(char* ws) {
    int tid = threadIdx.x;
    int* cnt = (int*)(ws + CNT_OFF);
    int* cur = (int*)(ws + CUR_OFF);
    for (int i = tid; i < S_DEN; i += 256) { cnt[i] = 0; cur[i] = 0; }
    if (tid < B_SZ) ((int*)(ws + CTR_OFF))[tid << 4] = 0;   // arrive counters
}

__global__ void prep_hist(const int* __restrict__ e_out, char* ws) {
    int e = blockIdx.x * blockDim.x + threadIdx.x;
    if (e < E_DEN) atomicAdd((int*)(ws + CNT_OFF) + e_out[e], 1);
}

__global__ __launch_bounds__(1024) void prep_scan(char* ws) {
    __shared__ int sb[2][2048];
    const int* cnt = (const int*)(ws + CNT_OFF);
    int* rowp = (int*)(ws + ROWPTR_OFF);
    int tid = threadIdx.x;
    for (int i = tid; i < 2048; i += 1024) sb[0][i] = (i < S_DEN) ? cnt[i] : 0;
    __syncthreads();
    int cur = 0;
    for (int d = 1; d < 2048; d <<= 1) {
        for (int i = tid; i < 2048; i += 1024)
            sb[1 - cur][i] = sb[cur][i] + ((i >= d) ? sb[cur][i - d] : 0);
        __syncthreads();
        cur ^= 1;
    }
    if (tid == 0) rowp[0] = 0;
    for (int i = tid; i < S_DEN; i += 1024) rowp[i + 1] = sb[cur][i];
    __syncthreads();
    if (tid == 0) {
        // Row splits at ~equal edge counts: chunk p owns rows [rs[p], rs[p+1]),
        // i.e. a contiguous, disjoint edge range (edges sorted by out).
        int* rs = (int*)(ws + RSPLIT_OFF);
        rs[0] = 0; rs[P_CH] = S_DEN;
        for (int p = 1; p < P_CH; ++p) {
            int target = (E_DEN / P_CH) * p;
            int lo = 0, hi = S_DEN;
            while (lo < hi) {
                int mid = (lo + hi) >> 1;
                int v = (mid == 0) ? 0 : sb[cur][mid - 1];   // rowp[mid]
                if (v >= target) hi = mid; else lo = mid + 1;
            }
            rs[p] = lo;
        }
    }
}

__global__ void prep_scatter(const int* __restrict__ e_in, const int* __restrict__ e_out,
                             const int* __restrict__ e_pdf, const float* __restrict__ e_prob,
                             char* ws) {
    int e = blockIdx.x * blockDim.x + threadIdx.x;
    if (e >= E_DEN) return;
    const int* rowp = (const int*)(ws + ROWPTR_OFF);
    int* cur = (int*)(ws + CUR_OFF);
    int4* recs = (int4*)(ws + REC_OFF);
    int o = e_out[e];
    int pos = rowp[o] + atomicAdd(&cur[o], 1);
    int4 r;
    r.x = e_in[e]; r.y = e_pdf[e];
    r.z = __float_as_int(e_prob[e]);
    r.w = o;
    recs[pos] = r;
}

// Pack per-chunk, padded to EPC with dummies (prob=0,d=0); srow per (chunk,thread).
__global__ void prep_pack(char* ws) {
    int slot = blockIdx.x * blockDim.x + threadIdx.x;
    if (slot >= P_CH * EPC) return;
    int p = slot >> 14;            // EPC = 16384
    int k = slot & (EPC - 1);
    const int* rowp = (const int*)(ws + ROWPTR_OFF);
    const int* rs = (const int*)(ws + RSPLIT_OFF);
    int ebase = rowp[rs[p]], eend = rowp[rs[p + 1]];
    uint2* pk = (uint2*)(ws + PACK_OFF);
    int idx = ebase + k;
    uint2 val;
    int myrow;
    if (idx < eend) {
        const int4* r4 = (const int4*)(ws + REC_OFF);
        int4 r = r4[idx];
        myrow = r.w;
        int nxt = (idx + 1 < eend) ? r4[idx + 1].w : myrow;  // chunk-last: d=0
        unsigned d = (unsigned)(nxt - myrow);
        if (d > 1023u) d = 1023u;                            // unreachable here
        val = make_uint2((unsigned)r.x | ((unsigned)r.y << 11) | (d << 22),
                         (unsigned)r.z);
    } else {
        val = make_uint2(0u, 0u);
        myrow = rs[p];
    }
    pk[slot] = val;
    if ((k & (EPT - 1)) == 0)
        ((int*)(ws + SROW_OFF))[(p << 9) + (k >> 5)] = myrow;
}

// ---------------- main kernel: 128 den blocks (32 utts x 4 chunks) + 32 num ----
// den: per-utterance 4-block group exchanges alpha through the LLC each step.
// Release = per-WAVE {vmcnt(0) drain -> arrive atomicAdd}; acquire = wave-0
// spin on the single per-utterance counter (target 32*(t+1)); psums read by
// 4 lanes post-spin. xrow(t+1) staging overlaps the spin window.
__global__ __launch_bounds__(NTHR, 2) void chain_fwd5(
    const float* __restrict__ x, const int* __restrict__ lengths,
    const float* __restrict__ den_leaky, const float* __restrict__ den_final,
    const int* __restrict__ num_in, const int* __restrict__ num_out,
    const int* __restrict__ num_pdf, const float* __restrict__ num_prob,
    const float* __restrict__ num_leaky, const float* __restrict__ num_final,
    char* __restrict__ ws)
{
    __shared__ float alpha[2048];
    __shared__ float xrow[2048];
    __shared__ float anew[2048];
    __shared__ float red[16];
    extern __shared__ float dynpad[];    // 60 KB occupancy pad (1 block/CU)
    const int tid = threadIdx.x;
    if (lengths[0] == -12345) dynpad[tid] = 1.f;   // never true; keeps pad live

    if (blockIdx.x < P_CH * B_SZ) {
        // =============== den chunk block ===============
        const int b = blockIdx.x & (B_SZ - 1);   // chunks {b, b+32, b+64, b+96}
        const int p = blockIdx.x >> 5;           // all land on XCD b%8
        const int len = lengths[b];
        const float* xb = x + (size_t)b * T_SZ * D_SZ;
        const int* rs = (const int*)(ws + RSPLIT_OFF);
        const int rlo = rs[p], rhi = rs[p + 1];
        float* anewg = (float*)(ws + ANEWG_OFF) + ((size_t)(b << 1) << 11);
        float* psumg = (float*)(ws + PSUM_OFF);
        int* ctr = (int*)(ws + CTR_OFF) + (b << 4);

        // Hoisted per-state constants (4 states/thread, s = tid + i*512).
        float lc[4], fc[4];
        #pragma unroll
        for (int i = 0; i < 4; ++i) {
            int s = tid + (i << 9);
            lc[i] = (s < S_DEN) ? DEN_C * den_leaky[s] : 0.f;
            fc[i] = (s < S_DEN) ? den_final[s] : 0.f;
        }
        #pragma unroll
        for (int i = 0; i < 4; ++i) {
            int s = tid + (i << 9);
            alpha[s] = lc[i] + ((s == 0) ? 1.f : 0.f);   // adash0 (asum=1)
            anew[s] = 0.f;
            xrow[s] = expclip(xb[s]);
        }

        const uint4* __restrict__ pk4 = (const uint4*)(ws + PACK_OFF);
        const int qb = (p << 13) + (tid << 4);   // uint4 index of my 32 edges
        const int row0 = ((const int*)(ws + SROW_OFF))[(p << 9) + tid];
        float logz = 0.f;
        // Superbatch-0 (16 edges) prefetched across step boundaries.
        uint4 c0 = pk4[qb + 0], c1 = pk4[qb + 1], c2 = pk4[qb + 2], c3 = pk4[qb + 3];
        uint4 c4 = pk4[qb + 4], c5 = pk4[qb + 5], c6 = pk4[qb + 6], c7 = pk4[qb + 7];
        __syncthreads();

        for (int t = 0; t < len; ++t) {
            const int par = t & 1;
            // Prefetch x(t+1) into registers (consumed at stage, pre-spin).
            const int tn = (t + 1 < len) ? t + 1 : t;
            const float* xq = xb + (size_t)tn * D_SZ;
            const float xn0 = xq[tid], xn1 = xq[tid + 512];
            const float xn2 = xq[tid + 1024], xn3 = xq[tid + 1536];

            // Edge phase: 2 superbatches x 16 edges, wraparound prefetch.
            float acc = 0.f, psum = 0.f;
            int row = row0;
            #pragma unroll
            for (int sb = 0; sb < 2; ++sb) {
                const int nq = qb + (((sb + 1) & 1) << 3);
                uint4 n0 = pk4[nq + 0], n1 = pk4[nq + 1], n2 = pk4[nq + 2], n3 = pk4[nq + 3];
                uint4 n4 = pk4[nq + 4], n5 = pk4[nq + 5], n6 = pk4[nq + 6], n7 = pk4[nq + 7];
                const unsigned w[16] = {c0.x, c0.z, c1.x, c1.z, c2.x, c2.z, c3.x, c3.z,
                                        c4.x, c4.z, c5.x, c5.z, c6.x, c6.z, c7.x, c7.z};
                const unsigned pr[16] = {c0.y, c0.w, c1.y, c1.w, c2.y, c2.w, c3.y, c3.w,
                                         c4.y, c4.w, c5.y, c5.w, c6.y, c6.w, c7.y, c7.w};
                float av[16], xv[16];
                #pragma unroll
                for (int i = 0; i < 16; ++i) av[i] = alpha[w[i] & 2047u];
                #pragma unroll
                for (int i = 0; i < 16; ++i) xv[i] = xrow[(w[i] >> 11) & 2047u];
                #pragma unroll
                for (int i = 0; i < 16; ++i) {
                    acc = __fmaf_rn(av[i] * __uint_as_float(pr[i]), xv[i], acc);
                    const unsigned d = w[i] >> 22;
                    if (d) { psum += acc; atomicAdd(&anew[row], acc); acc = 0.f; row += (int)d; }
                }
                c0 = n0; c1 = n1; c2 = n2; c3 = n3;
                c4 = n4; c5 = n5; c6 = n6; c7 = n7;
            }
            psum += acc;
            if (acc != 0.f) atomicAdd(&anew[row], acc);

            // Block partial-asum reduce into red[0..7].
            #pragma unroll
            for (int o = 32; o > 0; o >>= 1) psum += __shfl_down(psum, o, 64);
            if ((tid & 63) == 0) red[tid >> 6] = psum;
            __syncthreads();                         // B1: anew + red complete

            // Publish slice + psum; per-wave drain + arrive (no extra barrier).
            float* ag = anewg + (par << 11);
            const int pidx = (b << 4) | (par << 3);
            if (tid == 0) {
                float bs = red[0]+red[1]+red[2]+red[3]+red[4]+red[5]+red[6]+red[7];
                stf_agent(&psumg[pidx + p], bs);
            }
            for (int r = rlo + tid; r < rhi; r += NTHR) {
                stf_agent(&ag[r], anew[r]); anew[r] = 0.f;
            }
            asm volatile("s_waitcnt vmcnt(0)" ::: "memory");  // this wave's stores at LLC
            if ((tid & 63) == 0)
                __hip_atomic_fetch_add(ctr, 1, __ATOMIC_RELAXED, __HIP_MEMORY_SCOPE_AGENT);

            // Stage xrow(t+1) during the spin window (edge pass done since B1).
            xrow[tid]        = expclip(xn0);
            xrow[tid + 512]  = expclip(xn1);
            xrow[tid + 1024] = expclip(xn2);
            xrow[tid + 1536] = expclip(xn3);

            // Wave-0 spin on the single arrive counter; 4 lanes fetch psums.
            if (tid < 64) {
                const int target = (P_CH * (NTHR / 64)) * (t + 1);   // 32*(t+1)
                int gd = 0;
                while (ldi_agent(ctr) < target) {
                    __builtin_amdgcn_s_sleep(1);
                    if (++gd > (1 << 15)) break;     // bail out instead of hanging
                }
                if (tid < 4) red[8 + tid] = ldf_agent(&psumg[pidx + tid]);
            }
            __syncthreads();                         // B2: slices + psums visible

            const float asum = red[8] + red[9] + red[10] + red[11];
            const float inv = 1.f / asum;
            // Reload full anew -> adash -> alpha (every block redundantly).
            #pragma unroll
            for (int i = 0; i < 4; ++i) {
                const int s = tid + (i << 9);
                float an = (s < S_DEN) ? ldf_agent(&ag[s]) : 0.f;
                alpha[s] = __fmaf_rn(an, inv, lc[i]);
            }
            logz += logf(asum);
            __syncthreads();                         // B3: alpha/xrow ready
        }

        if (p == 0) {   // final dot over full alpha (resident in LDS)
            float fs = alpha[tid] * fc[0] + alpha[tid + 512] * fc[1]
                     + alpha[tid + 1024] * fc[2] + alpha[tid + 1536] * fc[3];
            #pragma unroll
            for (int o = 32; o > 0; o >>= 1) fs += __shfl_down(fs, o, 64);
            if ((tid & 63) == 0) red[tid >> 6] = fs;
            __syncthreads();
            if (tid == 0) {
                float tot = red[0]+red[1]+red[2]+red[3]+red[4]+red[5]+red[6]+red[7];
                ((float*)(ws + TOTD_OFF))[b] = logz + logf(tot);
            }
        }
    } else {
        // =============== num: one block per utterance, LDS-local ===============
        const int b = blockIdx.x - P_CH * B_SZ;
        const int len = lengths[b];
        const float* xb = x + (size_t)b * T_SZ * D_SZ;
        float* nalpha = alpha;            // [512]
        float* nanew  = anew;             // [512]
        const float lk = num_leaky[(b << 9) + tid];
        const float fn = num_final[(b << 9) + tid];
        // Hoist this utterance's edges into registers (4 edges/thread).
        int ein[4], eout[4], epdf[4]; float eprb[4];
        #pragma unroll
        for (int k = 0; k < 4; ++k) {
            int e = (b << 11) + tid + (k << 9);
            ein[k] = num_in[e]; eout[k] = num_out[e];
            epdf[k] = num_pdf[e]; eprb[k] = num_prob[e];
        }
        nalpha[tid] = NUM_C * lk + ((tid == 0) ? 1.f : 0.f);
        nanew[tid] = 0.f;
        #pragma unroll
        for (int i = 0; i < 4; ++i) xrow[tid + (i << 9)] = expclip(xb[tid + (i << 9)]);
        float logz = 0.f;
        __syncthreads();

        for (int t = 0; t < len; ++t) {
            const int tn = (t + 1 < len) ? t + 1 : t;
            const float* xq = xb + (size_t)tn * D_SZ;
            const float xn0 = xq[tid], xn1 = xq[tid + 512];
            const float xn2 = xq[tid + 1024], xn3 = xq[tid + 1536];
            #pragma unroll
            for (int k = 0; k < 4; ++k) {
                float v = nalpha[ein[k]] * eprb[k] * xrow[epdf[k]];
                atomicAdd(&nanew[eout[k]], v);
            }
            __syncthreads();
            float ps = nanew[tid];
            #pragma unroll
            for (int o = 32; o > 0; o >>= 1) ps += __shfl_down(ps, o, 64);
            if ((tid & 63) == 0) red[tid >> 6] = ps;
            __syncthreads();
            float asum = 0.f;
            #pragma unroll
            for (int i = 0; i < 8; ++i) asum += red[i];
            nalpha[tid] = __fmaf_rn(NUM_C * lk, asum, nanew[tid]) * (1.f / asum);
            nanew[tid] = 0.f;
            xrow[tid]        = expclip(xn0);
            xrow[tid + 512]  = expclip(xn1);
            xrow[tid + 1024] = expclip(xn2);
            xrow[tid + 1536] = expclip(xn3);
            logz += logf(asum);
            __syncthreads();
        }
        float fs = nalpha[tid] * fn;
        #pragma unroll
        for (int o = 32; o > 0; o >>= 1) fs += __shfl_down(fs, o, 64);
        if ((tid & 63) == 0) red[tid >> 6] = fs;
        __syncthreads();
        if (tid == 0) {
            float tot = 0.f;
            #pragma unroll
            for (int i = 0; i < 8; ++i) tot += red[i];
            ((float*)(ws + TOTN_OFF))[b] = logz + logf(tot);
        }
    }
}

__global__ void combine2(const char* __restrict__ ws, const int* __restrict__ lengths,
                         float* __restrict__ out) {
    const float* totd = (const float*)(ws + TOTD_OFF);
    const float* totn = (const float*)(ws + TOTN_OFF);
    int tid = threadIdx.x;
    float v = 0.f, l = 0.f;
    if (tid < B_SZ) { v = totd[tid] - totn[tid]; l = (float)lengths[tid]; }
    #pragma unroll
    for (int o = 32; o > 0; o >>= 1) { v += __shfl_down(v, o, 64); l += __shfl_down(l, o, 64); }
    if (tid == 0) out[0] = v / l;
}

// ===================== round-1 fallback (used only if ws too small) ==========
__global__ __launch_bounds__(1024) void chain_fwd_kernel(
    const float* __restrict__ x, const int* __restrict__ lengths,
    const int* __restrict__ den_in, const int* __restrict__ den_out,
    const int* __restrict__ den_pdf, const float* __restrict__ den_prob,
    const float* __restrict__ den_leaky, const float* __restrict__ den_final,
    const int* __restrict__ num_in, const int* __restrict__ num_out,
    const int* __restrict__ num_pdf, const float* __restrict__ num_prob,
    const float* __restrict__ num_leaky, const float* __restrict__ num_final,
    float* __restrict__ part)
{
    __shared__ float xrow[D_SZ];
    __shared__ float alpha[S_DEN];
    __shared__ float anew[S_DEN];
    __shared__ float red[17];
    const int tid = threadIdx.x;
    const int nthr = 1024;
    const bool is_den = blockIdx.x < B_SZ;
    const int b = blockIdx.x & (B_SZ - 1);
    int S, E;
    const int *e_in, *e_out, *e_pdf;
    const float *e_prob, *leaky, *fin;
    float coeff;
    if (is_den) {
        S = S_DEN; E = E_DEN;
        e_in = den_in; e_out = den_out; e_pdf = den_pdf; e_prob = den_prob;
        leaky = den_leaky; fin = den_final; coeff = DEN_C;
    } else {
        S = S_NUM; E = E_NUM;
        e_in = num_in + b * E_NUM; e_out = num_out + b * E_NUM;
        e_pdf = num_pdf + b * E_NUM; e_prob = num_prob + b * E_NUM;
        leaky = num_leaky + b * S_NUM; fin = num_final + b * S_NUM;
        coeff = NUM_C;
    }
    const int len = lengths[b];
    const float* xb = x + (size_t)b * T_SZ * D_SZ;
    for (int s = tid; s < S; s += nthr)
        alpha[s] = coeff * leaky[s] + (s == 0 ? 1.0f : 0.0f);
    float logz = 0.0f;
    for (int t = 0; t < len; ++t) {
        for (int s = tid; s < S; s += nthr) anew[s] = 0.0f;
        const float* xt = xb + (size_t)t * D_SZ;
        for (int d = tid; d < D_SZ; d += nthr)
            xrow[d] = __expf(fminf(fmaxf(xt[d], -30.0f), 30.0f));
        __syncthreads();
        for (int e = tid; e < E; e += nthr) {
            float v = alpha[e_in[e]] * e_prob[e] * xrow[e_pdf[e]];
            atomicAdd(&anew[e_out[e]], v);
        }
        __syncthreads();
        float ps = 0.0f;
        for (int s = tid; s < S; s += nthr) ps += anew[s];
        #pragma unroll
        for (int off = 32; off > 0; off >>= 1) ps += __shfl_down(ps, off, 64);
        if ((tid & 63) == 0) red[tid >> 6] = ps;
        __syncthreads();
        if (tid < 64) {
            float v = (tid < 16) ? red[tid] : 0.0f;
            #pragma unroll
            for (int off = 8; off > 0; off >>= 1) v += __shfl_down(v, off, 64);
            if (tid == 0) red[16] = v;
        }
        __syncthreads();
        const float asum = red[16];
        const float inv = 1.0f / asum;
        for (int s = tid; s < S; s += nthr)
            alpha[s] = (anew[s] + coeff * leaky[s] * asum) * inv;
        logz += logf(asum);
        __syncthreads();
    }
    float fs = 0.0f;
    for (int s = tid; s < S; s += nthr) fs += alpha[s] * fin[s];
    #pragma unroll
    for (int off = 32; off > 0; off >>= 1) fs += __shfl_down(fs, off, 64);
    if ((tid & 63) == 0) red[tid >> 6] = fs;
    __syncthreads();
    if (tid < 64) {
        float v = (tid < 16) ? red[tid] : 0.0f;
        #pragma unroll
        for (int off = 8; off > 0; off >>= 1) v += __shfl_down(v, off, 64);
        if (tid == 0) part[blockIdx.x] = logz + logf(v);
    }
}

__global__ void combine_kernel(const float* __restrict__ part,
                               const int* __restrict__ lengths,
                               float* __restrict__ out)
{
    int tid = threadIdx.x;
    float v = 0.0f, l = 0.0f;
    if (tid < B_SZ) { v = part[tid] - part[B_SZ + tid]; l = (float)lengths[tid]; }
    #pragma unroll
    for (int off = 32; off > 0; off >>= 1) { v += __shfl_down(v, off, 64); l += __shfl_down(l, off, 64); }
    if (tid == 0) out[0] = v / l;
}

// ---------------------------------------------------------------------------
extern "C" void kernel_launch(void* const* d_in, const int* in_sizes, int n_in,
                              void* d_out, int out_size, void* d_ws, size_t ws_size,
                              hipStream_t stream)
{
    const float* x          = (const float*)d_in[0];
    const int*   lengths    = (const int*)  d_in[1];
    const int*   den_in_p   = (const int*)  d_in[2];
    const int*   den_out_p  = (const int*)  d_in[3];
    const int*   den_pdf_p  = (const int*)  d_in[4];
    const float* den_prob_p = (const float*)d_in[5];
    const float* den_leaky  = (const float*)d_in[6];
    const float* den_final  = (const float*)d_in[7];
    const int*   num_in_p   = (const int*)  d_in[8];
    const int*   num_out_p  = (const int*)  d_in[9];
    const int*   num_pdf_p  = (const int*)  d_in[10];
    const float* num_prob_p = (const float*)d_in[11];
    const float* num_leaky  = (const float*)d_in[12];
    const float* num_final  = (const float*)d_in[13];

    if (ws_size >= WS_BYTES) {
        char* ws = (char*)d_ws;
        hipLaunchKernelGGL(prep_init, dim3(1), dim3(256), 0, stream, ws);
        hipLaunchKernelGGL(prep_hist, dim3((E_DEN + 255) / 256), dim3(256), 0, stream,
                           den_out_p, ws);
        hipLaunchKernelGGL(prep_scan, dim3(1), dim3(1024), 0, stream, ws);
        hipLaunchKernelGGL(prep_scatter, dim3((E_DEN + 255) / 256), dim3(256), 0, stream,
                           den_in_p, den_out_p, den_pdf_p, den_prob_p, ws);
        hipLaunchKernelGGL(prep_pack, dim3((P_CH * EPC + 255) / 256), dim3(256), 0, stream, ws);
        // 60 KB dynamic pad: 24.6 KB static + 60 KB > 80 KB -> one block/CU, so
        // all 160 blocks co-resident (spin-safe) with private LDS pipes.
        hipLaunchKernelGGL(chain_fwd5, dim3(P_CH * B_SZ + B_SZ), dim3(NTHR), 60000, stream,
                           x, lengths, den_leaky, den_final,
                           num_in_p, num_out_p, num_pdf_p, num_prob_p,
                           num_leaky, num_final, ws);
        hipLaunchKernelGGL(combine2, dim3(1), dim3(64), 0, stream,
                           ws, lengths, (float*)d_out);
    } else {
        float* part = (float*)d_ws;
        hipLaunchKernelGGL(chain_fwd_kernel, dim3(2 * B_SZ), dim3(1024), 0, stream,
                           x, lengths,
                           den_in_p, den_out_p, den_pdf_p, den_prob_p, den_leaky, den_final,
                           num_in_p, num_out_p, num_pdf_p, num_prob_p, num_leaky, num_final,
                           part);
        hipLaunchKernelGGL(combine_kernel, dim3(1), dim3(64), 0, stream,
                           part, lengths, (float*)d_out);
    }
}

// Round 5
// 2710.477 us; speedup vs baseline: 1.7617x; 1.0300x over previous
//
#include <hip/hip_runtime.h>
#include <math.h>

// Problem constants (match setup_inputs in the reference).
#define B_SZ   32
#define T_SZ   400
#define D_SZ   2048
#define S_DEN  2000
#define E_DEN  60000
#define S_NUM  512
#define E_NUM  2048
#define DEN_C  1e-5f
#define NUM_C  1e-20f

#define P_CH   8          // den edge-chunks (CUs) per utterance
#define NTHR   512        // threads per block (8 waves)
#define EPT    16         // edges per thread (whole list lives in 8 VGPR uint4s)
#define EPC    8192       // padded edges per chunk = NTHR*EPT

// ---- workspace layout (bytes). REC (prep only) overlaid by ANEWG (main only).
#define REC_OFF     0u          // int4[E_DEN] CSR {in,pdf,prob,out} sorted by out
#define ANEWG_OFF   0u          // float[B][2][2048] exchange buffer (524,288 B)
#define PACK_OFF    960000u     // uint2[P_CH*EPC] packed {in|pdf<<11|drow<<22, prob}
#define ROWPTR_OFF  1484288u    // int[S_DEN+1]
#define CNT_OFF     1492352u    // int[S_DEN]
#define CUR_OFF     1500352u    // int[S_DEN]
#define SROW_OFF    1508352u    // int[P_CH*NTHR] per-(chunk,thread) start row
#define RSPLIT_OFF  1524736u    // int[P_CH+1] chunk row splits
#define PSUM_OFF    1524800u    // float[B][2][16] partial asums (64B lines)
#define CTR_OFF     1528896u    // int[B][16]: [0]=arrive ctr, [1]=init ctr
#define XCD_OFF     1530944u    // int[B][8] per-chunk XCC_ID
#define TOTD_OFF    1531968u    // float[B]
#define TOTN_OFF    1532096u    // float[B]
#define WS_BYTES    1532224u

__device__ __forceinline__ float expclip(float v) {
    return __expf(fminf(fmaxf(v, -30.f), 30.f));
}
// Agent-scope (device-coherent) accesses: relaxed atomics emit sc-bit
// write-through/bypass ops WITHOUT whole-L2 writeback (round-1 lesson:
// __threadfence costs a full L2 flush per call on gfx950).
__device__ __forceinline__ float ldf_agent(const float* p) {
    return __hip_atomic_load(p, __ATOMIC_RELAXED, __HIP_MEMORY_SCOPE_AGENT);
}
__device__ __forceinline__ int ldi_agent(const int* p) {
    return __hip_atomic_load(p, __ATOMIC_RELAXED, __HIP_MEMORY_SCOPE_AGENT);
}
__device__ __forceinline__ void stf_agent(float* p, float v) {
    __hip_atomic_store(p, v, __ATOMIC_RELAXED, __HIP_MEMORY_SCOPE_AGENT);
}
__device__ __forceinline__ void sti_agent(int* p, int v) {
    __hip_atomic_store(p, v, __ATOMIC_RELAXED, __HIP_MEMORY_SCOPE_AGENT);
}

// ---------------- prep kernels ----------------
__global__ void prep_init(char* ws) {
    int tid = threadIdx.x;
    int* cnt = (int*)(ws + CNT_OFF);
    int* cur = (int*)(ws + CUR_OFF);
    for (int i = tid; i < S_DEN; i += 256) { cnt[i] = 0; cur[i] = 0; }
    int* ctr = (int*)(ws + CTR_OFF);
    for (int i = tid; i < B_SZ * 16; i += 256) ctr[i] = 0;
    int* xcd = (int*)(ws + XCD_OFF);
    if (tid < B_SZ * 8) xcd[tid] = 0;
}

__global__ void prep_hist(const int* __restrict__ e_out, char* ws) {
    int e = blockIdx.x * blockDim.x + threadIdx.x;
    if (e < E_DEN) atomicAdd((int*)(ws + CNT_OFF) + e_out[e], 1);
}

__global__ __launch_bounds__(1024) void prep_scan(char* ws) {
    __shared__ int sb[2][2048];
    const int* cnt = (const int*)(ws + CNT_OFF);
    int* rowp = (int*)(ws + ROWPTR_OFF);
    int tid = threadIdx.x;
    for (int i = tid; i < 2048; i += 1024) sb[0][i] = (i < S_DEN) ? cnt[i] : 0;
    __syncthreads();
    int cur = 0;
    for (int d = 1; d < 2048; d <<= 1) {
        for (int i = tid; i < 2048; i += 1024)
            sb[1 - cur][i] = sb[cur][i] + ((i >= d) ? sb[cur][i - d] : 0);
        __syncthreads();
        cur ^= 1;
    }
    if (tid == 0) rowp[0] = 0;
    for (int i = tid; i < S_DEN; i += 1024) rowp[i + 1] = sb[cur][i];
    __syncthreads();
    if (tid == 0) {
        // Row splits at ~equal edge counts: chunk p owns rows [rs[p], rs[p+1]),
        // i.e. a contiguous, disjoint edge range (edges sorted by out).
        int* rs = (int*)(ws + RSPLIT_OFF);
        rs[0] = 0; rs[P_CH] = S_DEN;
        for (int p = 1; p < P_CH; ++p) {
            int target = (E_DEN / P_CH) * p;
            int lo = 0, hi = S_DEN;
            while (lo < hi) {
                int mid = (lo + hi) >> 1;
                int v = (mid == 0) ? 0 : sb[cur][mid - 1];   // rowp[mid]
                if (v >= target) hi = mid; else lo = mid + 1;
            }
            rs[p] = lo;
        }
    }
}

__global__ void prep_scatter(const int* __restrict__ e_in, const int* __restrict__ e_out,
                             const int* __restrict__ e_pdf, const float* __restrict__ e_prob,
                             char* ws) {
    int e = blockIdx.x * blockDim.x + threadIdx.x;
    if (e >= E_DEN) return;
    const int* rowp = (const int*)(ws + ROWPTR_OFF);
    int* cur = (int*)(ws + CUR_OFF);
    int4* recs = (int4*)(ws + REC_OFF);
    int o = e_out[e];
    int pos = rowp[o] + atomicAdd(&cur[o], 1);
    int4 r;
    r.x = e_in[e]; r.y = e_pdf[e];
    r.z = __float_as_int(e_prob[e]);
    r.w = o;
    recs[pos] = r;
}

// Pack per-chunk, padded to EPC with dummies (prob=0,d=0); srow per (chunk,thread).
__global__ void prep_pack(char* ws) {
    int slot = blockIdx.x * blockDim.x + threadIdx.x;
    if (slot >= P_CH * EPC) return;
    int p = slot >> 13;            // EPC = 8192
    int k = slot & (EPC - 1);
    const int* rowp = (const int*)(ws + ROWPTR_OFF);
    const int* rs = (const int*)(ws + RSPLIT_OFF);
    int ebase = rowp[rs[p]], eend = rowp[rs[p + 1]];
    uint2* pk = (uint2*)(ws + PACK_OFF);
    int idx = ebase + k;
    uint2 val;
    int myrow;
    if (idx < eend) {
        const int4* r4 = (const int4*)(ws + REC_OFF);
        int4 r = r4[idx];
        myrow = r.w;
        int nxt = (idx + 1 < eend) ? r4[idx + 1].w : myrow;  // chunk-last: d=0
        unsigned d = (unsigned)(nxt - myrow);
        if (d > 1023u) d = 1023u;                            // unreachable here
        val = make_uint2((unsigned)r.x | ((unsigned)r.y << 11) | (d << 22),
                         (unsigned)r.z);
    } else {
        val = make_uint2(0u, 0u);
        myrow = rs[p];
    }
    pk[slot] = val;
    if ((k & (EPT - 1)) == 0)
        ((int*)(ws + SROW_OFF))[(p << 9) + (k >> 4)] = myrow;
}

// ---------------- main kernel: 256 den blocks (32 utts x 8 chunks) -----------
// num is folded into chunk-0 of each utterance and runs inside the spin window.
// Chunks {b, b+32, ..., b+224} are all == b (mod 8) -> same XCD under
// round-robin placement; verified at runtime via HW_REG_XCC_ID. If verified,
// publish stores are PLAIN (stay dirty in the shared XCD L2 -- no MALL/HBM
// write-through); flag RMW and all exchange loads stay agent-scope (TCC
// tag-check returns dirty L2 lines). If not verified -> agent stores (round-4
// path), correct under any placement.
__global__ __launch_bounds__(NTHR, 2) void chain_fwd6(
    const float* __restrict__ x, const int* __restrict__ lengths,
    const float* __restrict__ den_leaky, const float* __restrict__ den_final,
    const int* __restrict__ num_in, const int* __restrict__ num_out,
    const int* __restrict__ num_pdf, const float* __restrict__ num_prob,
    const float* __restrict__ num_leaky, const float* __restrict__ num_final,
    char* __restrict__ ws)
{
    __shared__ float alpha[2048];
    __shared__ float xrow[2048];
    __shared__ float anew[2048];
    __shared__ float nalpha[S_NUM];
    __shared__ float nanew[S_NUM];
    __shared__ float red[24];
    __shared__ int sSame;
    extern __shared__ float dynpad[];    // 56 KB occupancy pad (1 block/CU)
    const int tid = threadIdx.x;
    if (lengths[0] == -12345) dynpad[tid] = 1.f;   // never true; keeps pad live

    const int b = blockIdx.x & (B_SZ - 1);
    const int p = blockIdx.x >> 5;
    const bool isNum = (p == 0);
    const int len = lengths[b];
    const float* xb = x + (size_t)b * T_SZ * D_SZ;
    const int* rs = (const int*)(ws + RSPLIT_OFF);
    const int rlo = rs[p], rhi = rs[p + 1];
    float* anewg = (float*)(ws + ANEWG_OFF) + ((size_t)(b << 1) << 11);
    float* psumg = (float*)(ws + PSUM_OFF);
    int* ctr = (int*)(ws + CTR_OFF) + (b << 4);
    int* xcdArr = (int*)(ws + XCD_OFF);

    // ---- pre-loop: XCD-group verification (one-time agent exchange) ----
    int myxcc = 0;
    asm volatile("s_getreg_b32 %0, hwreg(HW_REG_XCC_ID)" : "=s"(myxcc));
    if (tid == 0) {
        sti_agent(&xcdArr[(b << 3) + p], myxcc + 1);   // +1: distinguish from 0-init
        asm volatile("s_waitcnt vmcnt(0)" ::: "memory");
        __hip_atomic_fetch_add(ctr + 1, 1, __ATOMIC_RELAXED, __HIP_MEMORY_SCOPE_AGENT);
    }
    if (tid < 64) {
        int gd = 0;
        while (ldi_agent(ctr + 1) < P_CH) {
            __builtin_amdgcn_s_sleep(2);
            if (++gd > (1 << 16)) break;               // bail out instead of hanging
        }
        int v = (tid < 8) ? ldi_agent(&xcdArr[(b << 3) + tid]) : -1;
        int v0 = __shfl(v, 0, 64);
        bool eq = (tid < 8) ? (v == v0 && v != 0) : true;
        unsigned long long m = __ballot(eq);
        if (tid == 0) sSame = (~m == 0ULL) ? 1 : 0;
    }

    // ---- hoisted per-state constants + LDS init ----
    float lc[4], fc[4];
    #pragma unroll
    for (int i = 0; i < 4; ++i) {
        int s = tid + (i << 9);
        lc[i] = (s < S_DEN) ? DEN_C * den_leaky[s] : 0.f;
        fc[i] = (s < S_DEN) ? den_final[s] : 0.f;
    }
    #pragma unroll
    for (int i = 0; i < 4; ++i) {
        int s = tid + (i << 9);
        alpha[s] = lc[i] + ((s == 0) ? 1.f : 0.f);     // adash0 (asum=1)
        anew[s] = 0.f;
        xrow[s] = expclip(xb[s]);
    }

    // num state (chunk-0 blocks only); edges hoisted into registers.
    float nlk = 0.f, nfn = 0.f, nlogz = 0.f;
    int nein[4], neout[4], nepdf[4]; float neprb[4];
    if (isNum) {
        nlk = num_leaky[(b << 9) + tid];
        nfn = num_final[(b << 9) + tid];
        #pragma unroll
        for (int k = 0; k < 4; ++k) {
            int e = (b << 11) + tid + (k << 9);
            nein[k] = num_in[e]; neout[k] = num_out[e];
            nepdf[k] = num_pdf[e]; neprb[k] = num_prob[e];
        }
        nalpha[tid] = NUM_C * nlk + ((tid == 0) ? 1.f : 0.f);
        nanew[tid] = 0.f;
    }

    // Whole per-thread edge list (16 edges = 8 uint4) lives in registers.
    const uint4* __restrict__ pk4 = (const uint4*)(ws + PACK_OFF);
    const int qb = (p << 12) + (tid << 3);
    const uint4 c0 = pk4[qb + 0], c1 = pk4[qb + 1], c2 = pk4[qb + 2], c3 = pk4[qb + 3];
    const uint4 c4 = pk4[qb + 4], c5 = pk4[qb + 5], c6 = pk4[qb + 6], c7 = pk4[qb + 7];
    const int row0 = ((const int*)(ws + SROW_OFF))[(p << 9) + tid];
    float logz = 0.f;
    __syncthreads();
    const bool fastSt = (sSame != 0);

    for (int t = 0; t < len; ++t) {
        const int par = t & 1;
        // Prefetch x(t+1) into registers (consumed at stage, pre-spin).
        const int tn = (t + 1 < len) ? t + 1 : t;
        const float* xq = xb + (size_t)tn * D_SZ;
        const float xn0 = xq[tid], xn1 = xq[tid + 512];
        const float xn2 = xq[tid + 1024], xn3 = xq[tid + 1536];

        // ---- den edge phase: 16 edges, registers -> LDS gathers ----
        float acc = 0.f, psum = 0.f;
        int row = row0;
        {
            const unsigned w[16] = {c0.x, c0.z, c1.x, c1.z, c2.x, c2.z, c3.x, c3.z,
                                    c4.x, c4.z, c5.x, c5.z, c6.x, c6.z, c7.x, c7.z};
            const unsigned pr[16] = {c0.y, c0.w, c1.y, c1.w, c2.y, c2.w, c3.y, c3.w,
                                     c4.y, c4.w, c5.y, c5.w, c6.y, c6.w, c7.y, c7.w};
            float av[16], xv[16];
            #pragma unroll
            for (int i = 0; i < 16; ++i) av[i] = alpha[w[i] & 2047u];
            #pragma unroll
            for (int i = 0; i < 16; ++i) xv[i] = xrow[(w[i] >> 11) & 2047u];
            #pragma unroll
            for (int i = 0; i < 16; ++i) {
                acc = __fmaf_rn(av[i] * __uint_as_float(pr[i]), xv[i], acc);
                const unsigned d = w[i] >> 22;
                if (d) { psum += acc; atomicAdd(&anew[row], acc); acc = 0.f; row += (int)d; }
            }
        }
        psum += acc;
        if (acc != 0.f) atomicAdd(&anew[row], acc);
        #pragma unroll
        for (int o = 32; o > 0; o >>= 1) psum += __shfl_down(psum, o, 64);
        if ((tid & 63) == 0) red[tid >> 6] = psum;
        __syncthreads();                         // B1: anew + red complete

        // ---- publish slice + psum; per-wave drain + arrive ----
        float* ag = anewg + (par << 11);
        const int pidx = ((b << 1) | par) << 4;
        if (tid == 0) {
            float bs = red[0]+red[1]+red[2]+red[3]+red[4]+red[5]+red[6]+red[7];
            if (fastSt) psumg[pidx + p] = bs;
            else        stf_agent(&psumg[pidx + p], bs);
        }
        if (fastSt) {
            for (int r = rlo + tid; r < rhi; r += NTHR) { ag[r] = anew[r]; anew[r] = 0.f; }
        } else {
            for (int r = rlo + tid; r < rhi; r += NTHR) { stf_agent(&ag[r], anew[r]); anew[r] = 0.f; }
        }
        asm volatile("s_waitcnt vmcnt(0)" ::: "memory");  // this wave's stores in L2
        if ((tid & 63) == 0)
            __hip_atomic_fetch_add(ctr, 1, __ATOMIC_RELAXED, __HIP_MEMORY_SCOPE_AGENT);

        // ---- num step for this utterance (chunk 0 only; hides in spin window) --
        if (isNum) {
            #pragma unroll
            for (int k = 0; k < 4; ++k) {
                float v = nalpha[nein[k]] * neprb[k] * xrow[nepdf[k]];
                atomicAdd(&nanew[neout[k]], v);
            }
            __syncthreads();                     // Bnum: nanew complete
            float ps = nanew[tid];
            #pragma unroll
            for (int o = 32; o > 0; o >>= 1) ps += __shfl_down(ps, o, 64);
            if ((tid & 63) == 0) red[8 + (tid >> 6)] = ps;
        }

        // Stage xrow(t+1) while peer chunks finish publishing.
        xrow[tid]        = expclip(xn0);
        xrow[tid + 512]  = expclip(xn1);
        xrow[tid + 1024] = expclip(xn2);
        xrow[tid + 1536] = expclip(xn3);

        // Wave-0 spin on the arrive counter; 8 lanes fetch den psums.
        if (tid < 64) {
            const int target = (P_CH * (NTHR / 64)) * (t + 1);   // 64*(t+1)
            int gd = 0;
            while (ldi_agent(ctr) < target) {
                __builtin_amdgcn_s_sleep(1);
                if (++gd > (1 << 15)) break;     // bail out instead of hanging
            }
            if (tid < 8) red[16 + tid] = ldf_agent(&psumg[pidx + tid]);
        }
        __syncthreads();                         // B2: slices + psums visible

        const float asum = red[16]+red[17]+red[18]+red[19]
                         + red[20]+red[21]+red[22]+red[23];
        const float inv = 1.f / asum;
        // Reload full anew -> adash -> alpha (every block redundantly).
        #pragma unroll
        for (int i = 0; i < 4; ++i) {
            const int s = tid + (i << 9);
            float an = (s < S_DEN) ? ldf_agent(&ag[s]) : 0.f;
            alpha[s] = __fmaf_rn(an, inv, lc[i]);
        }
        logz += logf(asum);
        if (isNum) {
            const float nasum = red[8]+red[9]+red[10]+red[11]
                              + red[12]+red[13]+red[14]+red[15];
            nalpha[tid] = __fmaf_rn(NUM_C * nlk, nasum, nanew[tid]) * (1.f / nasum);
            nanew[tid] = 0.f;
            nlogz += logf(nasum);
        }
        __syncthreads();                         // B3: alpha/xrow ready
    }

    if (isNum) {   // chunk 0: den final dot + num final dot
        float fs = alpha[tid] * fc[0] + alpha[tid + 512] * fc[1]
                 + alpha[tid + 1024] * fc[2] + alpha[tid + 1536] * fc[3];
        #pragma unroll
        for (int o = 32; o > 0; o >>= 1) fs += __shfl_down(fs, o, 64);
        if ((tid & 63) == 0) red[tid >> 6] = fs;
        __syncthreads();
        if (tid == 0) {
            float tot = red[0]+red[1]+red[2]+red[3]+red[4]+red[5]+red[6]+red[7];
            ((float*)(ws + TOTD_OFF))[b] = logz + logf(tot);
        }
        __syncthreads();
        float nfs = nalpha[tid] * nfn;
        #pragma unroll
        for (int o = 32; o > 0; o >>= 1) nfs += __shfl_down(nfs, o, 64);
        if ((tid & 63) == 0) red[tid >> 6] = nfs;
        __syncthreads();
        if (tid == 0) {
            float tot = red[0]+red[1]+red[2]+red[3]+red[4]+red[5]+red[6]+red[7];
            ((float*)(ws + TOTN_OFF))[b] = nlogz + logf(tot);
        }
    }
}

__global__ void combine2(const char* __restrict__ ws, const int* __restrict__ lengths,
                         float* __restrict__ out) {
    const float* totd = (const float*)(ws + TOTD_OFF);
    const float* totn = (const float*)(ws + TOTN_OFF);
    int tid = threadIdx.x;
    float v = 0.f, l = 0.f;
    if (tid < B_SZ) { v = totd[tid] - totn[tid]; l = (float)lengths[tid]; }
    #pragma unroll
    for (int o = 32; o > 0; o >>= 1) { v += __shfl_down(v, o, 64); l += __shfl_down(l, o, 64); }
    if (tid == 0) out[0] = v / l;
}

// ===================== round-1 fallback (used only if ws too small) ==========
__global__ __launch_bounds__(1024) void chain_fwd_kernel(
    const float* __restrict__ x, const int* __restrict__ lengths,
    const int* __restrict__ den_in, const int* __restrict__ den_out,
    const int* __restrict__ den_pdf, const float* __restrict__ den_prob,
    const float* __restrict__ den_leaky, const float* __restrict__ den_final,
    const int* __restrict__ num_in, const int* __restrict__ num_out,
    const int* __restrict__ num_pdf, const float* __restrict__ num_prob,
    const float* __restrict__ num_leaky, const float* __restrict__ num_final,
    float* __restrict__ part)
{
    __shared__ float xrow[D_SZ];
    __shared__ float alpha[S_DEN];
    __shared__ float anew[S_DEN];
    __shared__ float red[17];
    const int tid = threadIdx.x;
    const int nthr = 1024;
    const bool is_den = blockIdx.x < B_SZ;
    const int b = blockIdx.x & (B_SZ - 1);
    int S, E;
    const int *e_in, *e_out, *e_pdf;
    const float *e_prob, *leaky, *fin;
    float coeff;
    if (is_den) {
        S = S_DEN; E = E_DEN;
        e_in = den_in; e_out = den_out; e_pdf = den_pdf; e_prob = den_prob;
        leaky = den_leaky; fin = den_final; coeff = DEN_C;
    } else {
        S = S_NUM; E = E_NUM;
        e_in = num_in + b * E_NUM; e_out = num_out + b * E_NUM;
        e_pdf = num_pdf + b * E_NUM; e_prob = num_prob + b * E_NUM;
        leaky = num_leaky + b * S_NUM; fin = num_final + b * S_NUM;
        coeff = NUM_C;
    }
    const int len = lengths[b];
    const float* xb = x + (size_t)b * T_SZ * D_SZ;
    for (int s = tid; s < S; s += nthr)
        alpha[s] = coeff * leaky[s] + (s == 0 ? 1.0f : 0.0f);
    float logz = 0.0f;
    for (int t = 0; t < len; ++t) {
        for (int s = tid; s < S; s += nthr) anew[s] = 0.0f;
        const float* xt = xb + (size_t)t * D_SZ;
        for (int d = tid; d < D_SZ; d += nthr)
            xrow[d] = __expf(fminf(fmaxf(xt[d], -30.0f), 30.0f));
        __syncthreads();
        for (int e = tid; e < E; e += nthr) {
            float v = alpha[e_in[e]] * e_prob[e] * xrow[e_pdf[e]];
            atomicAdd(&anew[e_out[e]], v);
        }
        __syncthreads();
        float ps = 0.0f;
        for (int s = tid; s < S; s += nthr) ps += anew[s];
        #pragma unroll
        for (int off = 32; off > 0; off >>= 1) ps += __shfl_down(ps, off, 64);
        if ((tid & 63) == 0) red[tid >> 6] = ps;
        __syncthreads();
        if (tid < 64) {
            float v = (tid < 16) ? red[tid] : 0.0f;
            #pragma unroll
            for (int off = 8; off > 0; off >>= 1) v += __shfl_down(v, off, 64);
            if (tid == 0) red[16] = v;
        }
        __syncthreads();
        const float asum = red[16];
        const float inv = 1.0f / asum;
        for (int s = tid; s < S; s += nthr)
            alpha[s] = (anew[s] + coeff * leaky[s] * asum) * inv;
        logz += logf(asum);
        __syncthreads();
    }
    float fs = 0.0f;
    for (int s = tid; s < S; s += nthr) fs += alpha[s] * fin[s];
    #pragma unroll
    for (int off = 32; off > 0; off >>= 1) fs += __shfl_down(fs, off, 64);
    if ((tid & 63) == 0) red[tid >> 6] = fs;
    __syncthreads();
    if (tid < 64) {
        float v = (tid < 16) ? red[tid] : 0.0f;
        #pragma unroll
        for (int off = 8; off > 0; off >>= 1) v += __shfl_down(v, off, 64);
        if (tid == 0) part[blockIdx.x] = logz + logf(v);
    }
}

__global__ void combine_kernel(const float* __restrict__ part,
                               const int* __restrict__ lengths,
                               float* __restrict__ out)
{
    int tid = threadIdx.x;
    float v = 0.0f, l = 0.0f;
    if (tid < B_SZ) { v = part[tid] - part[B_SZ + tid]; l = (float)lengths[tid]; }
    #pragma unroll
    for (int off = 32; off > 0; off >>= 1) { v += __shfl_down(v, off, 64); l += __shfl_down(l, off, 64); }
    if (tid == 0) out[0] = v / l;
}

// ---------------------------------------------------------------------------
extern "C" void kernel_launch(void* const* d_in, const int* in_sizes, int n_in,
                              void* d_out, int out_size, void* d_ws, size_t ws_size,
                              hipStream_t stream)
{
    const float* x          = (const float*)d_in[0];
    const int*   lengths    = (const int*)  d_in[1];
    const int*   den_in_p   = (const int*)  d_in[2];
    const int*   den_out_p  = (const int*)  d_in[3];
    const int*   den_pdf_p  = (const int*)  d_in[4];
    const float* den_prob_p = (const float*)d_in[5];
    const float* den_leaky  = (const float*)d_in[6];
    const float* den_final  = (const float*)d_in[7];
    const int*   num_in_p   = (const int*)  d_in[8];
    const int*   num_out_p  = (const int*)  d_in[9];
    const int*   num_pdf_p  = (const int*)  d_in[10];
    const float* num_prob_p = (const float*)d_in[11];
    const float* num_leaky  = (const float*)d_in[12];
    const float* num_final  = (const float*)d_in[13];

    if (ws_size >= WS_BYTES) {
        char* ws = (char*)d_ws;
        hipLaunchKernelGGL(prep_init, dim3(1), dim3(256), 0, stream, ws);
        hipLaunchKernelGGL(prep_hist, dim3((E_DEN + 255) / 256), dim3(256), 0, stream,
                           den_out_p, ws);
        hipLaunchKernelGGL(prep_scan, dim3(1), dim3(1024), 0, stream, ws);
        hipLaunchKernelGGL(prep_scatter, dim3((E_DEN + 255) / 256), dim3(256), 0, stream,
                           den_in_p, den_out_p, den_pdf_p, den_prob_p, ws);
        hipLaunchKernelGGL(prep_pack, dim3((P_CH * EPC + 255) / 256), dim3(256), 0, stream, ws);
        // 56 KB dynamic pad: ~28.2 KB static + 56 KB > 80 KB -> one block/CU;
        // 256 blocks on 256 CUs, all co-resident (spin-safe), private LDS pipes.
        hipLaunchKernelGGL(chain_fwd6, dim3(P_CH * B_SZ), dim3(NTHR), 57344, stream,
                           x, lengths, den_leaky, den_final,
                           num_in_p, num_out_p, num_pdf_p, num_prob_p,
                           num_leaky, num_final, ws);
        hipLaunchKernelGGL(combine2, dim3(1), dim3(64), 0, stream,
                           ws, lengths, (float*)d_out);
    } else {
        float* part = (float*)d_ws;
        hipLaunchKernelGGL(chain_fwd_kernel, dim3(2 * B_SZ), dim3(1024), 0, stream,
                           x, lengths,
                           den_in_p, den_out_p, den_pdf_p, den_prob_p, den_leaky, den_final,
                           num_in_p, num_out_p, num_pdf_p, num_prob_p, num_leaky, num_final,
                           part);
        hipLaunchKernelGGL(combine_kernel, dim3(1), dim3(64), 0, stream,
                           part, lengths, (float*)d_out);
    }
}